// Round 5
// baseline (336.057 us; speedup 1.0000x reference)
//
#include <hip/hip_runtime.h>

#define HW   128
#define OHW  256
#define G0n  64
#define HID  256
#define NOUT 1728
#define NB   4

typedef __attribute__((ext_vector_type(8))) short bf16x8;
typedef __attribute__((ext_vector_type(4))) float f32x4;
typedef __attribute__((ext_vector_type(4))) unsigned int u32x4;
typedef __attribute__((ext_vector_type(2))) unsigned int u32x2;

__device__ __forceinline__ unsigned short f2bf(float f) {
    unsigned int u = __builtin_bit_cast(unsigned int, f);
    u += 0x7fffu + ((u >> 16) & 1u);
    return (unsigned short)(u >> 16);
}
__device__ __forceinline__ float bflo(unsigned int d) {
    return __builtin_bit_cast(float, d << 16);
}
__device__ __forceinline__ float bfhi(unsigned int d) {
    return __builtin_bit_cast(float, d & 0xffff0000u);
}

// ---------------- Kernel 0: w2 [256][1728] f32 -> w2t [1728][256] bf16 (LDS tiled) ----
__global__ __launch_bounds__(256) void prep_w2t(const float* __restrict__ w2,
                                                unsigned short* __restrict__ w2t) {
    __shared__ float t[64][65];
    int kb = blockIdx.x & 3, cb = blockIdx.x >> 2;
    int lc = threadIdx.x & 63, lr = threadIdx.x >> 6;
    #pragma unroll
    for (int i = 0; i < 16; ++i) {
        int kk = lr + i * 4;
        t[kk][lc] = w2[(kb * 64 + kk) * NOUT + cb * 64 + lc];
    }
    __syncthreads();
    #pragma unroll
    for (int i = 0; i < 16; ++i) {
        int cc = lr + i * 4;
        w2t[(cb * 64 + cc) * 256 + kb * 64 + lc] = f2bf(t[lc][cc]);
    }
}

// ---------------- Kernel 1: 5x5 SAME conv + bias + ReLU, 4 outputs/thread ----------------
__global__ __launch_bounds__(256) void conv5_relu_kernel(
    const float* __restrict__ x, const float* __restrict__ cw,
    const float* __restrict__ cb, float* __restrict__ feat)
{
    int idx = blockIdx.x * 256 + threadIdx.x;
    int w4 = (idx & 31) * 4;
    int h  = (idx >> 5) & 127;
    int g  = (idx >> 12) & 63;
    int n  = idx >> 18;
    float bv = cb[g];
    float a[4] = {bv, bv, bv, bv};
    const float* wp = cw + g * 75;
    #pragma unroll
    for (int ci = 0; ci < 3; ++ci) {
        const float* xr = x + (n * 3 + ci) * (HW * HW);
        #pragma unroll
        for (int ki = 0; ki < 5; ++ki) {
            int hh = h + ki - 2;
            if (hh < 0 || hh >= HW) continue;
            const float* row = xr + hh * HW;
            float f[8];
            if (w4 != 0 && w4 != 124) {
                float2 u0 = *(const float2*)(row + w4 - 2);
                float2 u1 = *(const float2*)(row + w4);
                float2 u2 = *(const float2*)(row + w4 + 2);
                float2 u3 = *(const float2*)(row + w4 + 4);
                f[0] = u0.x; f[1] = u0.y; f[2] = u1.x; f[3] = u1.y;
                f[4] = u2.x; f[5] = u2.y; f[6] = u3.x; f[7] = u3.y;
            } else {
                #pragma unroll
                for (int j = 0; j < 8; ++j) {
                    int ww = w4 - 2 + j;
                    f[j] = (ww >= 0 && ww < HW) ? row[ww] : 0.0f;
                }
            }
            float wt[5];
            #pragma unroll
            for (int kj = 0; kj < 5; ++kj) wt[kj] = wp[ci * 25 + ki * 5 + kj];
            #pragma unroll
            for (int j = 0; j < 4; ++j)
                #pragma unroll
                for (int kj = 0; kj < 5; ++kj)
                    a[j] = fmaf(f[j + kj], wt[kj], a[j]);
        }
    }
    float4 o;
    o.x = fmaxf(a[0], 0.f); o.y = fmaxf(a[1], 0.f);
    o.z = fmaxf(a[2], 0.f); o.w = fmaxf(a[3], 0.f);
    *(float4*)&feat[((n * G0n + g) * HW + h) * HW + w4] = o;
}

// ---------------- Kernel 2: fused MFMA Pos2Weight GEMM + dynamic conv + mean-shift ----
// 512 threads = 8 waves (2M x 4N). M = 64 px. afrag 2 m-tiles/wave (64 VGPR).
// Einsum: thread = (px, n, kt-half), uniform 12-iter t3 loop, shfl_xor reduce.
__global__ __launch_bounds__(512, 4) void fused_metasr_mfma(
    const float* __restrict__ feat, const unsigned short* __restrict__ w2t,
    const float* __restrict__ pos,  const float* __restrict__ w1,
    const float* __restrict__ b1,   const float* __restrict__ b2,
    float* __restrict__ out)
{
    __shared__ __align__(16) unsigned short AL[64 * 260];        // 33280 B (Ahid ∪ lwc)
    __shared__ __align__(16) unsigned short FT[64 * 6 * 4 * 8];  // 24576 B [ci][r6][n4][c8]

    const int tid = threadIdx.x;
    const int bx = blockIdx.x & 31, by = blockIdx.x >> 5;
    const int oy0 = by * 8, ox0 = bx * 8;
    const int h0 = by * 4,  w0 = bx * 4;

    // ---- stage feat halo tile as bf16 ----
    for (int i = tid; i < 64 * 6 * 4 * 8; i += 512) {
        int c  = i & 7;
        int n  = (i >> 3) & 3;
        int r  = (i >> 5) % 6;
        int ci = (i >> 5) / 6;
        int gh = h0 - 1 + r, gw = w0 - 1 + c;
        float v = 0.0f;
        if (c < 6 && gh >= 0 && gh < HW && gw >= 0 && gw < HW)
            v = feat[((n * G0n + ci) * HW + gh) * HW + gw];
        FT[i] = f2bf(v);
    }

    // ---- hidden = relu(pos @ w1 + b1) -> AL[px][256] bf16 (32 k per thread) ----
    {
        int px = tid >> 3, q = tid & 7;
        int rr = (oy0 + (px >> 3)) * OHW + (ox0 + (px & 7));
        float p0 = pos[rr * 3 + 0], p1 = pos[rr * 3 + 1], p2 = pos[rr * 3 + 2];
        #pragma unroll
        for (int j = 0; j < 8; ++j) {
            int k0 = q * 32 + j * 4;
            float4 wa = *(const float4*)&w1[k0];
            float4 wb = *(const float4*)&w1[HID + k0];
            float4 wc = *(const float4*)&w1[2 * HID + k0];
            float4 bb = *(const float4*)&b1[k0];
            unsigned short h0s = f2bf(fmaxf(fmaf(p0, wa.x, fmaf(p1, wb.x, fmaf(p2, wc.x, bb.x))), 0.f));
            unsigned short h1s = f2bf(fmaxf(fmaf(p0, wa.y, fmaf(p1, wb.y, fmaf(p2, wc.y, bb.y))), 0.f));
            unsigned short h2s = f2bf(fmaxf(fmaf(p0, wa.z, fmaf(p1, wb.z, fmaf(p2, wc.z, bb.z))), 0.f));
            unsigned short h3s = f2bf(fmaxf(fmaf(p0, wa.w, fmaf(p1, wb.w, fmaf(p2, wc.w, bb.w))), 0.f));
            u32x2 pk;
            pk.x = (unsigned)h0s | ((unsigned)h1s << 16);
            pk.y = (unsigned)h2s | ((unsigned)h3s << 16);
            *(u32x2*)&AL[px * 260 + k0] = pk;
        }
    }
    __syncthreads();

    // ---- load A fragments: wave (mh, nq); 2 m-tiles per wave ----
    const int lane = tid & 63, wid = tid >> 6;
    const int mh = wid >> 2, nq = wid & 3;
    const int cl = lane & 15, hi = lane >> 4;
    bf16x8 afrag[2][8];
    #pragma unroll
    for (int m = 0; m < 2; ++m)
        #pragma unroll
        for (int k8 = 0; k8 < 8; ++k8)
            afrag[m][k8] = *(const bf16x8*)&AL[(mh * 32 + m * 16 + cl) * 260 + k8 * 32 + hi * 8];

    // einsum thread roles: (px, n, kt-half)
    const int epx = tid >> 3, en = (tid >> 1) & 3, half = tid & 1;
    const int iy = epx >> 4;              // low-res row within tile (0..3)
    const int ix = (epx & 7) >> 1;        // low-res col within tile (0..3)
    const bool selhi = (ix >= 2);
    const bool podd  = (ix & 1) != 0;
    float oacc0 = 0.f, oacc1 = 0.f, oacc2 = 0.f;

    for (int ch = 0; ch < 9; ++ch) {
        // ---- MFMA: 192 cols of lw for this chunk ----
        f32x4 acc[2][3];
        #pragma unroll
        for (int m = 0; m < 2; ++m)
            #pragma unroll
            for (int j = 0; j < 3; ++j)
                acc[m][j] = (f32x4){0.f, 0.f, 0.f, 0.f};
        #pragma unroll
        for (int ks = 0; ks < 8; ++ks) {
            bf16x8 bfrag[3];
            #pragma unroll
            for (int j = 0; j < 3; ++j) {
                int col = nq * 48 + j * 16 + cl;
                bfrag[j] = *(const bf16x8*)&w2t[(ch * 192 + col) * 256 + ks * 32 + hi * 8];
            }
            #pragma unroll
            for (int m = 0; m < 2; ++m)
                #pragma unroll
                for (int j = 0; j < 3; ++j)
                    acc[m][j] = __builtin_amdgcn_mfma_f32_16x16x32_bf16(
                        afrag[m][ks], bfrag[j], acc[m][j], 0, 0, 0);
        }

        __syncthreads();   // einsum(ch-1) readers / afrag loads done
        // ---- C-write (+bias) into lwc (= AL): [px][kt*4+c] bf16 ----
        #pragma unroll
        for (int j = 0; j < 3; ++j) {
            int col = nq * 48 + j * 16 + cl;
            float bv = b2[ch * 192 + col];
            int kt = col / 3;
            int c  = col - kt * 3;
            #pragma unroll
            for (int m = 0; m < 2; ++m)
                #pragma unroll
                for (int r = 0; r < 4; ++r)
                    AL[(mh * 32 + m * 16 + hi * 4 + r) * 260 + kt * 4 + c] = f2bf(acc[m][j][r] + bv);
        }
        __syncthreads();

        // ---- einsum partial: this thread's 32-kt half of the 64-kt chunk ----
        int k0h = ch * 64 + half * 32;
        int t3a = k0h / 3;
        #pragma unroll
        for (int it = 0; it < 12; ++it) {
            int t3 = t3a + it;
            t3 = t3 > 191 ? 191 : t3;
            int ci = t3 / 3;
            int di = t3 - ci * 3;
            const char* fp = (const char*)FT + ci * 384 + (iy + di) * 64 + en * 16;
            u32x4 w = *(const u32x4*)fp;
            unsigned a0 = selhi ? w.y : w.x;
            unsigned b0 = selhi ? w.z : w.y;
            float loa = bflo(a0), hia = bfhi(a0);
            float lob = bflo(b0), hib = bfhi(b0);
            float f0 = podd ? hia : loa;
            float f1 = podd ? lob : hia;
            float f2 = podd ? hib : lob;
            int kb = 3 * t3 - ch * 64;
            #pragma unroll
            for (int dj = 0; dj < 3; ++dj) {
                int ktg = kb + dj;
                float fv = dj == 0 ? f0 : (dj == 1 ? f1 : f2);
                unsigned rel = (unsigned)(ktg - (half << 5));
                fv = (rel < 32u) ? fv : 0.0f;
                int kta = ktg < 0 ? 0 : (ktg > 63 ? 63 : ktg);
                u32x2 d = *(const u32x2*)((const char*)AL + epx * 520 + kta * 8);
                oacc0 = fmaf(fv, bflo(d.x), oacc0);
                oacc1 = fmaf(fv, bfhi(d.x), oacc1);
                oacc2 = fmaf(fv, bflo(d.y), oacc2);
            }
        }
    }

    // ---- reduce the two kt-halves, write output + mean shift ----
    oacc0 += __shfl_xor(oacc0, 1);
    oacc1 += __shfl_xor(oacc1, 1);
    oacc2 += __shfl_xor(oacc2, 1);
    if (half == 0) {
        int oy = oy0 + (epx >> 3), ox = ox0 + (epx & 7);
        out[((en * 3 + 0) * OHW + oy) * OHW + ox] = oacc0 + 0.4488f * 255.0f;
        out[((en * 3 + 1) * OHW + oy) * OHW + ox] = oacc1 + 0.4371f * 255.0f;
        out[((en * 3 + 2) * OHW + oy) * OHW + ox] = oacc2 + 0.4040f * 255.0f;
    }
}

extern "C" void kernel_launch(void* const* d_in, const int* in_sizes, int n_in,
                              void* d_out, int out_size, void* d_ws, size_t ws_size,
                              hipStream_t stream) {
    (void)in_sizes; (void)n_in; (void)out_size; (void)ws_size;
    const float* x      = (const float*)d_in[0];
    const float* posm   = (const float*)d_in[1];
    const float* conv_w = (const float*)d_in[2];
    const float* conv_b = (const float*)d_in[3];
    const float* w1     = (const float*)d_in[4];
    const float* b1     = (const float*)d_in[5];
    const float* w2     = (const float*)d_in[6];
    const float* b2     = (const float*)d_in[7];
    float* out = (float*)d_out;

    unsigned short* w2t = (unsigned short*)d_ws;                 // 884736 B
    float* feat = (float*)((char*)d_ws + 884736);                // 16.8 MB

    prep_w2t<<<108, 256, 0, stream>>>(w2, w2t);
    conv5_relu_kernel<<<(NB * G0n * HW * 32) / 256, 256, 0, stream>>>(x, conv_w, conv_b, feat);
    fused_metasr_mfma<<<1024, 512, 0, stream>>>(feat, w2t, posm, w1, b1, b2, out);
}

// Round 7
// 242.855 us; speedup vs baseline: 1.3838x; 1.3838x over previous
//
#include <hip/hip_runtime.h>

#define HW   128
#define OHW  256
#define G0n  64
#define HID  256
#define NOUT 1728
#define NB   4

typedef __attribute__((ext_vector_type(8))) short bf16x8;
typedef __attribute__((ext_vector_type(4))) float f32x4;
typedef __attribute__((ext_vector_type(4))) unsigned int u32x4;
typedef __attribute__((ext_vector_type(2))) unsigned int u32x2;

__device__ __forceinline__ unsigned short f2bf(float f) {
    unsigned int u = __builtin_bit_cast(unsigned int, f);
    u += 0x7fffu + ((u >> 16) & 1u);
    return (unsigned short)(u >> 16);
}
__device__ __forceinline__ float bflo(unsigned int d) {
    return __builtin_bit_cast(float, d << 16);
}
__device__ __forceinline__ float bfhi(unsigned int d) {
    return __builtin_bit_cast(float, d & 0xffff0000u);
}

// ---------------- Kernel 0: w2 [256][1728] f32 -> w2t [1728][256] bf16 (LDS tiled) ----
__global__ __launch_bounds__(256) void prep_w2t(const float* __restrict__ w2,
                                                unsigned short* __restrict__ w2t) {
    __shared__ float t[64][65];
    int kb = blockIdx.x & 3, cb = blockIdx.x >> 2;
    int lc = threadIdx.x & 63, lr = threadIdx.x >> 6;
    #pragma unroll
    for (int i = 0; i < 16; ++i) {
        int kk = lr + i * 4;
        t[kk][lc] = w2[(kb * 64 + kk) * NOUT + cb * 64 + lc];
    }
    __syncthreads();
    #pragma unroll
    for (int i = 0; i < 16; ++i) {
        int cc = lr + i * 4;
        w2t[(cb * 64 + cc) * 256 + kb * 64 + lc] = f2bf(t[lc][cc]);
    }
}

// ---------------- Kernel 1: 5x5 SAME conv + bias + ReLU, 4 outputs/thread ----------------
__global__ __launch_bounds__(256) void conv5_relu_kernel(
    const float* __restrict__ x, const float* __restrict__ cw,
    const float* __restrict__ cb, float* __restrict__ feat)
{
    int idx = blockIdx.x * 256 + threadIdx.x;
    int w4 = (idx & 31) * 4;
    int h  = (idx >> 5) & 127;
    int g  = (idx >> 12) & 63;
    int n  = idx >> 18;
    float bv = cb[g];
    float a[4] = {bv, bv, bv, bv};
    const float* wp = cw + g * 75;
    #pragma unroll
    for (int ci = 0; ci < 3; ++ci) {
        const float* xr = x + (n * 3 + ci) * (HW * HW);
        #pragma unroll
        for (int ki = 0; ki < 5; ++ki) {
            int hh = h + ki - 2;
            if (hh < 0 || hh >= HW) continue;
            const float* row = xr + hh * HW;
            float f[8];
            if (w4 != 0 && w4 != 124) {
                float2 u0 = *(const float2*)(row + w4 - 2);
                float2 u1 = *(const float2*)(row + w4);
                float2 u2 = *(const float2*)(row + w4 + 2);
                float2 u3 = *(const float2*)(row + w4 + 4);
                f[0] = u0.x; f[1] = u0.y; f[2] = u1.x; f[3] = u1.y;
                f[4] = u2.x; f[5] = u2.y; f[6] = u3.x; f[7] = u3.y;
            } else {
                #pragma unroll
                for (int j = 0; j < 8; ++j) {
                    int ww = w4 - 2 + j;
                    f[j] = (ww >= 0 && ww < HW) ? row[ww] : 0.0f;
                }
            }
            float wt[5];
            #pragma unroll
            for (int kj = 0; kj < 5; ++kj) wt[kj] = wp[ci * 25 + ki * 5 + kj];
            #pragma unroll
            for (int j = 0; j < 4; ++j)
                #pragma unroll
                for (int kj = 0; kj < 5; ++kj)
                    a[j] = fmaf(f[j + kj], wt[kj], a[j]);
        }
    }
    float4 o;
    o.x = fmaxf(a[0], 0.f); o.y = fmaxf(a[1], 0.f);
    o.z = fmaxf(a[2], 0.f); o.w = fmaxf(a[3], 0.f);
    *(float4*)&feat[((n * G0n + g) * HW + h) * HW + w4] = o;
}

// ---------------- Kernel 2a: barrier-free MFMA GEMM -> lw bf16 [65536][1728] ----------
// 256 threads (4 waves = 4 N-quarters), M = 64 pixels/block. A in regs, B from L2,
// C straight to HBM. No __syncthreads in the main loop.
__global__ __launch_bounds__(256) void gemm_lw(
    const unsigned short* __restrict__ w2t, const float* __restrict__ pos,
    const float* __restrict__ w1, const float* __restrict__ b1,
    const float* __restrict__ b2, unsigned short* __restrict__ lw)
{
    __shared__ __align__(16) unsigned short AL[64 * 260];

    const int tid = threadIdx.x;
    const int bx = blockIdx.x & 31, by = blockIdx.x >> 5;
    const int oy0 = by * 8, ox0 = bx * 8;

    // hidden = relu(pos @ w1 + b1) -> AL[px][256]
    {
        int px = tid >> 2, q = tid & 3;
        int rr = (oy0 + (px >> 3)) * OHW + (ox0 + (px & 7));
        float p0 = pos[rr * 3 + 0], p1 = pos[rr * 3 + 1], p2 = pos[rr * 3 + 2];
        #pragma unroll
        for (int j = 0; j < 16; ++j) {
            int k0 = q * 4 + j * 16;
            float4 wa = *(const float4*)&w1[k0];
            float4 wb = *(const float4*)&w1[HID + k0];
            float4 wc = *(const float4*)&w1[2 * HID + k0];
            float4 bb = *(const float4*)&b1[k0];
            unsigned short h0s = f2bf(fmaxf(fmaf(p0, wa.x, fmaf(p1, wb.x, fmaf(p2, wc.x, bb.x))), 0.f));
            unsigned short h1s = f2bf(fmaxf(fmaf(p0, wa.y, fmaf(p1, wb.y, fmaf(p2, wc.y, bb.y))), 0.f));
            unsigned short h2s = f2bf(fmaxf(fmaf(p0, wa.z, fmaf(p1, wb.z, fmaf(p2, wc.z, bb.z))), 0.f));
            unsigned short h3s = f2bf(fmaxf(fmaf(p0, wa.w, fmaf(p1, wb.w, fmaf(p2, wc.w, bb.w))), 0.f));
            u32x2 pk;
            pk.x = (unsigned)h0s | ((unsigned)h1s << 16);
            pk.y = (unsigned)h2s | ((unsigned)h3s << 16);
            *(u32x2*)&AL[px * 260 + k0] = pk;
        }
    }
    __syncthreads();

    const int lane = tid & 63, nq = tid >> 6;
    const int cl = lane & 15, hi = lane >> 4;
    bf16x8 afrag[4][8];
    #pragma unroll
    for (int m = 0; m < 4; ++m)
        #pragma unroll
        for (int k8 = 0; k8 < 8; ++k8)
            afrag[m][k8] = *(const bf16x8*)&AL[(m * 16 + cl) * 260 + k8 * 32 + hi * 8];

    const size_t rowbase = (size_t)blockIdx.x * 64;

    for (int ch = 0; ch < 9; ++ch) {
        f32x4 acc[4][3];
        #pragma unroll
        for (int m = 0; m < 4; ++m)
            #pragma unroll
            for (int j = 0; j < 3; ++j)
                acc[m][j] = (f32x4){0.f, 0.f, 0.f, 0.f};
        #pragma unroll
        for (int ks = 0; ks < 8; ++ks) {
            bf16x8 bfrag[3];
            #pragma unroll
            for (int j = 0; j < 3; ++j) {
                int col = ch * 192 + nq * 48 + j * 16 + cl;
                bfrag[j] = *(const bf16x8*)&w2t[(size_t)col * 256 + ks * 32 + hi * 8];
            }
            #pragma unroll
            for (int m = 0; m < 4; ++m)
                #pragma unroll
                for (int j = 0; j < 3; ++j)
                    acc[m][j] = __builtin_amdgcn_mfma_f32_16x16x32_bf16(
                        afrag[m][ks], bfrag[j], acc[m][j], 0, 0, 0);
        }
        // write C (+bias) to lw[row][kt*3+c] bf16
        #pragma unroll
        for (int j = 0; j < 3; ++j) {
            int col = ch * 192 + nq * 48 + j * 16 + cl;
            float bv = b2[col];
            #pragma unroll
            for (int m = 0; m < 4; ++m)
                #pragma unroll
                for (int r = 0; r < 4; ++r) {
                    size_t row = rowbase + m * 16 + hi * 4 + r;
                    lw[row * NOUT + col] = f2bf(acc[m][j][r] + bv);
                }
        }
    }
}

// ---------------- Kernel 2b: einsum (dynamic conv) + mean-shift -------------------------
// thread = (px, n). lw row streamed as 8-ci groups (27 x b128, all indices static).
__global__ __launch_bounds__(256) void einsum_out(
    const float* __restrict__ feat, const unsigned short* __restrict__ lw,
    float* __restrict__ out)
{
    __shared__ __align__(8) unsigned short FT[64 * 6 * 4 * 6];   // 18432 B, [ci][r6][n4][c6]

    const int tid = threadIdx.x;
    const int bx = blockIdx.x & 31, by = blockIdx.x >> 5;
    const int oy0 = by * 8, ox0 = bx * 8;
    const int h0 = by * 4,  w0 = bx * 4;

    for (int i = tid; i < 64 * 6 * 4 * 6; i += 256) {
        int c = i % 6;
        int t = i / 6;
        int n = t & 3;
        t >>= 2;
        int r  = t % 6;
        int ci = t / 6;
        int gh = h0 - 1 + r, gw = w0 - 1 + c;
        float v = 0.0f;
        if (gh >= 0 && gh < HW && gw >= 0 && gw < HW)
            v = feat[((n * G0n + ci) * HW + gh) * HW + gw];
        FT[i] = f2bf(v);
    }
    __syncthreads();

    const int px = tid >> 2, n = tid & 3;
    const int iy = (px >> 3) >> 1;
    const int ix = (px & 7) >> 1;
    const bool podd = (ix & 1) != 0;
    const int ixa = ix & ~1;

    const u32x4* lwp = (const u32x4*)(lw + ((size_t)blockIdx.x * 64 + px) * NOUT);
    float o0 = 0.f, o1 = 0.f, o2 = 0.f;

    for (int g = 0; g < 8; ++g) {
        // 8 ci per group = 216 shorts = 27 x b128, 16B-aligned (432 B stride)
        u32x4 LA[14], LB[14];
        #pragma unroll
        for (int t = 0; t < 14; ++t) LA[t] = lwp[g * 27 + t];
        #pragma unroll
        for (int t = 0; t < 14; ++t) LB[t] = (t + 13 < 27) ? lwp[g * 27 + 13 + t] : (u32x4){0,0,0,0};

        #pragma unroll
        for (int cl8 = 0; cl8 < 8; ++cl8) {
            int ci = g * 8 + cl8;
            // f-values: fv[di*3+dj] = FT[ci][iy+di][n][ix+dj]
            float fv[9];
            #pragma unroll
            for (int di = 0; di < 3; ++di) {
                int rb = ((ci * 6 + iy + di) * 4 + n) * 6 + ixa;
                unsigned u0 = *(const unsigned*)&FT[rb];
                unsigned u1 = *(const unsigned*)&FT[rb + 2];
                fv[di * 3 + 0] = podd ? bfhi(u0) : bflo(u0);
                fv[di * 3 + 1] = podd ? bflo(u1) : bfhi(u0);
                fv[di * 3 + 2] = podd ? bfhi(u1) : bflo(u1);
            }
            // 27 lw values at static positions
            #pragma unroll
            for (int ktl = 0; ktl < 9; ++ktl) {
                #pragma unroll
                for (int c = 0; c < 3; ++c) {
                    int idx = cl8 * 27 + ktl * 3 + c;          // short index in group, static
                    unsigned d;
                    if (idx < 108) d = LA[idx >> 3][(idx >> 1) & 3];
                    else { int i2 = idx - 104; d = LB[i2 >> 3][(i2 >> 1) & 3]; }
                    float v = (idx & 1) ? bfhi(d) : bflo(d);
                    if (c == 0) o0 = fmaf(fv[ktl], v, o0);
                    else if (c == 1) o1 = fmaf(fv[ktl], v, o1);
                    else o2 = fmaf(fv[ktl], v, o2);
                }
            }
        }
    }

    int oy = oy0 + (px >> 3), ox = ox0 + (px & 7);
    out[((n * 3 + 0) * OHW + oy) * OHW + ox] = o0 + 0.4488f * 255.0f;
    out[((n * 3 + 1) * OHW + oy) * OHW + ox] = o1 + 0.4371f * 255.0f;
    out[((n * 3 + 2) * OHW + oy) * OHW + ox] = o2 + 0.4040f * 255.0f;
}

// ---------------- Fallback: r3 fused kernel (proven, used when ws too small) ----------
__global__ __launch_bounds__(256, 2) void fused_metasr_mfma(
    const float* __restrict__ feat, const unsigned short* __restrict__ w2t,
    const float* __restrict__ pos,  const float* __restrict__ w1,
    const float* __restrict__ b1,   const float* __restrict__ b2,
    float* __restrict__ out)
{
    __shared__ __align__(16) unsigned short AL[64 * 260];
    __shared__ __align__(16) unsigned short FT[64 * 6 * 4 * 8];

    const int tid = threadIdx.x;
    const int bx = blockIdx.x & 31, by = blockIdx.x >> 5;
    const int oy0 = by * 8, ox0 = bx * 8;
    const int h0 = by * 4,  w0 = bx * 4;

    for (int i = tid; i < 64 * 6 * 4 * 8; i += 256) {
        int c  = i & 7;
        int n  = (i >> 3) & 3;
        int r  = (i >> 5) % 6;
        int ci = (i >> 5) / 6;
        int gh = h0 - 1 + r, gw = w0 - 1 + c;
        float v = 0.0f;
        if (c < 6 && gh >= 0 && gh < HW && gw >= 0 && gw < HW)
            v = feat[((n * G0n + ci) * HW + gh) * HW + gw];
        FT[i] = f2bf(v);
    }
    {
        int px = tid >> 2, q = tid & 3;
        int rr = (oy0 + (px >> 3)) * OHW + (ox0 + (px & 7));
        float p0 = pos[rr * 3 + 0], p1 = pos[rr * 3 + 1], p2 = pos[rr * 3 + 2];
        #pragma unroll
        for (int j = 0; j < 16; ++j) {
            int k0 = q * 4 + j * 16;
            float4 wa = *(const float4*)&w1[k0];
            float4 wb = *(const float4*)&w1[HID + k0];
            float4 wc = *(const float4*)&w1[2 * HID + k0];
            float4 bb = *(const float4*)&b1[k0];
            unsigned short h0s = f2bf(fmaxf(fmaf(p0, wa.x, fmaf(p1, wb.x, fmaf(p2, wc.x, bb.x))), 0.f));
            unsigned short h1s = f2bf(fmaxf(fmaf(p0, wa.y, fmaf(p1, wb.y, fmaf(p2, wc.y, bb.y))), 0.f));
            unsigned short h2s = f2bf(fmaxf(fmaf(p0, wa.z, fmaf(p1, wb.z, fmaf(p2, wc.z, bb.z))), 0.f));
            unsigned short h3s = f2bf(fmaxf(fmaf(p0, wa.w, fmaf(p1, wb.w, fmaf(p2, wc.w, bb.w))), 0.f));
            u32x2 pk;
            pk.x = (unsigned)h0s | ((unsigned)h1s << 16);
            pk.y = (unsigned)h2s | ((unsigned)h3s << 16);
            *(u32x2*)&AL[px * 260 + k0] = pk;
        }
    }
    __syncthreads();

    const int lane = tid & 63, nq = tid >> 6;
    const int cl = lane & 15, hi = lane >> 4;
    bf16x8 afrag[4][8];
    #pragma unroll
    for (int m = 0; m < 4; ++m)
        #pragma unroll
        for (int k8 = 0; k8 < 8; ++k8)
            afrag[m][k8] = *(const bf16x8*)&AL[(m * 16 + cl) * 260 + k8 * 32 + hi * 8];

    const int epx = tid >> 2, en = tid & 3;
    const int iy = (epx >> 3) >> 1;
    const int ix = (epx & 7) >> 1;
    const bool selhi = (ix >= 2);
    const bool podd  = (ix & 1) != 0;
    const unsigned lwbase = (unsigned)(epx * 520);
    float oacc0 = 0.f, oacc1 = 0.f, oacc2 = 0.f;

    for (int ch = 0; ch < 9; ++ch) {
        f32x4 acc[4][3];
        #pragma unroll
        for (int m = 0; m < 4; ++m)
            #pragma unroll
            for (int j = 0; j < 3; ++j)
                acc[m][j] = (f32x4){0.f, 0.f, 0.f, 0.f};
        #pragma unroll
        for (int kh = 0; kh < 2; ++kh) {
            #pragma unroll
            for (int kk = 0; kk < 4; ++kk) {
                bf16x8 bfrag[3];
                #pragma unroll
                for (int j = 0; j < 3; ++j) {
                    int col = nq * 48 + j * 16 + cl;
                    bfrag[j] = *(const bf16x8*)&w2t[(ch * 192 + col) * 256 + kh * 128 + kk * 32 + hi * 8];
                }
                #pragma unroll
                for (int m = 0; m < 4; ++m)
                    #pragma unroll
                    for (int j = 0; j < 3; ++j)
                        acc[m][j] = __builtin_amdgcn_mfma_f32_16x16x32_bf16(
                            afrag[m][kh * 4 + kk], bfrag[j], acc[m][j], 0, 0, 0);
            }
        }
        __syncthreads();
        #pragma unroll
        for (int j = 0; j < 3; ++j) {
            int col = nq * 48 + j * 16 + cl;
            float bv = b2[ch * 192 + col];
            int kt = col / 3;
            int c  = col - kt * 3;
            #pragma unroll
            for (int m = 0; m < 4; ++m)
                #pragma unroll
                for (int r = 0; r < 4; ++r) {
                    int row = m * 16 + hi * 4 + r;
                    AL[row * 260 + kt * 4 + c] = f2bf(acc[m][j][r] + bv);
                }
        }
        __syncthreads();

        int k0 = ch * 64;
        int t3a = k0 / 3;
        int t3b = (k0 + 63) / 3;
        auto do_t3 = [&](int t3, bool guard) {
            int ci = t3 / 3;
            int di = t3 - ci * 3;
            const char* fp = (const char*)FT + ci * 384 + (iy + di) * 64 + en * 16;
            u32x4 w = *(const u32x4*)fp;
            unsigned a0 = selhi ? w.y : w.x;
            unsigned b0 = selhi ? w.z : w.y;
            float loa = bflo(a0), hia = bfhi(a0);
            float lob = bflo(b0), hib = bfhi(b0);
            float f0 = podd ? hia : loa;
            float f1 = podd ? lob : hia;
            float f2 = podd ? hib : lob;
            int ktb = 3 * t3 - k0;
            #pragma unroll
            for (int dj = 0; dj < 3; ++dj) {
                int kt = ktb + dj;
                float fvv = dj == 0 ? f0 : (dj == 1 ? f1 : f2);
                if (guard) {
                    fvv = ((unsigned)kt < 64u) ? fvv : 0.0f;
                    kt = kt < 0 ? 0 : (kt > 63 ? 63 : kt);
                }
                u32x2 d = *(const u32x2*)((const char*)AL + lwbase + (unsigned)(kt * 8));
                oacc0 = fmaf(fvv, bflo(d.x), oacc0);
                oacc1 = fmaf(fvv, bfhi(d.x), oacc1);
                oacc2 = fmaf(fvv, bflo(d.y), oacc2);
            }
        };
        do_t3(t3a, true);
        for (int t3 = t3a + 1; t3 < t3b; ++t3) do_t3(t3, false);
        do_t3(t3b, true);
    }

    int oy = oy0 + (epx >> 3), ox = ox0 + (epx & 7);
    out[((en * 3 + 0) * OHW + oy) * OHW + ox] = oacc0 + 0.4488f * 255.0f;
    out[((en * 3 + 1) * OHW + oy) * OHW + ox] = oacc1 + 0.4371f * 255.0f;
    out[((en * 3 + 2) * OHW + oy) * OHW + ox] = oacc2 + 0.4040f * 255.0f;
}

extern "C" void kernel_launch(void* const* d_in, const int* in_sizes, int n_in,
                              void* d_out, int out_size, void* d_ws, size_t ws_size,
                              hipStream_t stream) {
    (void)in_sizes; (void)n_in; (void)out_size;
    const float* x      = (const float*)d_in[0];
    const float* posm   = (const float*)d_in[1];
    const float* conv_w = (const float*)d_in[2];
    const float* conv_b = (const float*)d_in[3];
    const float* w1     = (const float*)d_in[4];
    const float* b1     = (const float*)d_in[5];
    const float* w2     = (const float*)d_in[6];
    const float* b2     = (const float*)d_in[7];
    float* out = (float*)d_out;

    unsigned short* w2t = (unsigned short*)d_ws;                     // 884,736 B
    float* feat = (float*)((char*)d_ws + 884736);                    // 16,777,216 B
    const size_t lw_off = 884736u + 16777216u;                       // 17,661,952
    const size_t lw_bytes = (size_t)65536 * NOUT * 2;                // 226,492,416
    unsigned short* lwbuf = (unsigned short*)((char*)d_ws + lw_off);

    prep_w2t<<<108, 256, 0, stream>>>(w2, w2t);
    conv5_relu_kernel<<<(NB * G0n * HW * 32) / 256, 256, 0, stream>>>(x, conv_w, conv_b, feat);

    if (ws_size >= lw_off + lw_bytes) {
        gemm_lw<<<1024, 256, 0, stream>>>(w2t, posm, w1, b1, b2, lwbuf);
        einsum_out<<<1024, 256, 0, stream>>>(feat, lwbuf, out);
    } else {
        fused_metasr_mfma<<<1024, 256, 0, stream>>>(feat, w2t, posm, w1, b1, b2, out);
    }
}

// Round 8
// 240.445 us; speedup vs baseline: 1.3976x; 1.0100x over previous
//
#include <hip/hip_runtime.h>

#define HW   128
#define OHW  256
#define G0n  64
#define HID  256
#define NOUT 1728
#define NB   4

typedef __attribute__((ext_vector_type(8))) short bf16x8;
typedef __attribute__((ext_vector_type(4))) float f32x4;
typedef __attribute__((ext_vector_type(4))) unsigned int u32x4;
typedef __attribute__((ext_vector_type(2))) unsigned int u32x2;

__device__ __forceinline__ unsigned short f2bf(float f) {
    unsigned int u = __builtin_bit_cast(unsigned int, f);
    u += 0x7fffu + ((u >> 16) & 1u);
    return (unsigned short)(u >> 16);
}
__device__ __forceinline__ float bflo(unsigned int d) {
    return __builtin_bit_cast(float, d << 16);
}
__device__ __forceinline__ float bfhi(unsigned int d) {
    return __builtin_bit_cast(float, d & 0xffff0000u);
}

// ---------------- Kernel 0: w2 [256][1728] f32 -> w2t [1728][256] bf16 (LDS tiled) ----
__global__ __launch_bounds__(256) void prep_w2t(const float* __restrict__ w2,
                                                unsigned short* __restrict__ w2t) {
    __shared__ float t[64][65];
    int kb = blockIdx.x & 3, cb = blockIdx.x >> 2;
    int lc = threadIdx.x & 63, lr = threadIdx.x >> 6;
    #pragma unroll
    for (int i = 0; i < 16; ++i) {
        int kk = lr + i * 4;
        t[kk][lc] = w2[(kb * 64 + kk) * NOUT + cb * 64 + lc];
    }
    __syncthreads();
    #pragma unroll
    for (int i = 0; i < 16; ++i) {
        int cc = lr + i * 4;
        w2t[(cb * 64 + cc) * 256 + kb * 64 + lc] = f2bf(t[lc][cc]);
    }
}

// ---------------- Kernel 1: 5x5 SAME conv + bias + ReLU, 4 outputs/thread ----------------
__global__ __launch_bounds__(256) void conv5_relu_kernel(
    const float* __restrict__ x, const float* __restrict__ cw,
    const float* __restrict__ cb, float* __restrict__ feat)
{
    int idx = blockIdx.x * 256 + threadIdx.x;
    int w4 = (idx & 31) * 4;
    int h  = (idx >> 5) & 127;
    int g  = (idx >> 12) & 63;
    int n  = idx >> 18;
    float bv = cb[g];
    float a[4] = {bv, bv, bv, bv};
    const float* wp = cw + g * 75;
    #pragma unroll
    for (int ci = 0; ci < 3; ++ci) {
        const float* xr = x + (n * 3 + ci) * (HW * HW);
        #pragma unroll
        for (int ki = 0; ki < 5; ++ki) {
            int hh = h + ki - 2;
            if (hh < 0 || hh >= HW) continue;
            const float* row = xr + hh * HW;
            float f[8];
            if (w4 != 0 && w4 != 124) {
                float2 u0 = *(const float2*)(row + w4 - 2);
                float2 u1 = *(const float2*)(row + w4);
                float2 u2 = *(const float2*)(row + w4 + 2);
                float2 u3 = *(const float2*)(row + w4 + 4);
                f[0] = u0.x; f[1] = u0.y; f[2] = u1.x; f[3] = u1.y;
                f[4] = u2.x; f[5] = u2.y; f[6] = u3.x; f[7] = u3.y;
            } else {
                #pragma unroll
                for (int j = 0; j < 8; ++j) {
                    int ww = w4 - 2 + j;
                    f[j] = (ww >= 0 && ww < HW) ? row[ww] : 0.0f;
                }
            }
            float wt[5];
            #pragma unroll
            for (int kj = 0; kj < 5; ++kj) wt[kj] = wp[ci * 25 + ki * 5 + kj];
            #pragma unroll
            for (int j = 0; j < 4; ++j)
                #pragma unroll
                for (int kj = 0; kj < 5; ++kj)
                    a[j] = fmaf(f[j + kj], wt[kj], a[j]);
        }
    }
    float4 o;
    o.x = fmaxf(a[0], 0.f); o.y = fmaxf(a[1], 0.f);
    o.z = fmaxf(a[2], 0.f); o.w = fmaxf(a[3], 0.f);
    *(float4*)&feat[((n * G0n + g) * HW + h) * HW + w4] = o;
}

// ---------------- Kernel 2a: MFMA GEMM -> lw bf16, LDS-repacked coalesced stores ------
// 256 threads (4 waves = 4 N-quarters), M = 64 pixels/block. A in regs, B from L2.
// C chunk staged in LDS (reuse AL), then stored as 16 rows x 64B segments per inst.
__global__ __launch_bounds__(256) void gemm_lw(
    const unsigned short* __restrict__ w2t, const float* __restrict__ pos,
    const float* __restrict__ w1, const float* __restrict__ b1,
    const float* __restrict__ b2, unsigned short* __restrict__ lw)
{
    __shared__ __align__(16) unsigned short AL[64 * 260];   // Ahid, then C-stage [64][200]

    const int tid = threadIdx.x;
    const int bx = blockIdx.x & 31, by = blockIdx.x >> 5;
    const int oy0 = by * 8, ox0 = bx * 8;

    // hidden = relu(pos @ w1 + b1) -> AL[px][256]
    {
        int px = tid >> 2, q = tid & 3;
        int rr = (oy0 + (px >> 3)) * OHW + (ox0 + (px & 7));
        float p0 = pos[rr * 3 + 0], p1 = pos[rr * 3 + 1], p2 = pos[rr * 3 + 2];
        #pragma unroll
        for (int j = 0; j < 16; ++j) {
            int k0 = q * 4 + j * 16;
            float4 wa = *(const float4*)&w1[k0];
            float4 wb = *(const float4*)&w1[HID + k0];
            float4 wc = *(const float4*)&w1[2 * HID + k0];
            float4 bb = *(const float4*)&b1[k0];
            unsigned short h0s = f2bf(fmaxf(fmaf(p0, wa.x, fmaf(p1, wb.x, fmaf(p2, wc.x, bb.x))), 0.f));
            unsigned short h1s = f2bf(fmaxf(fmaf(p0, wa.y, fmaf(p1, wb.y, fmaf(p2, wc.y, bb.y))), 0.f));
            unsigned short h2s = f2bf(fmaxf(fmaf(p0, wa.z, fmaf(p1, wb.z, fmaf(p2, wc.z, bb.z))), 0.f));
            unsigned short h3s = f2bf(fmaxf(fmaf(p0, wa.w, fmaf(p1, wb.w, fmaf(p2, wc.w, bb.w))), 0.f));
            u32x2 pk;
            pk.x = (unsigned)h0s | ((unsigned)h1s << 16);
            pk.y = (unsigned)h2s | ((unsigned)h3s << 16);
            *(u32x2*)&AL[px * 260 + k0] = pk;
        }
    }
    __syncthreads();

    const int lane = tid & 63, nq = tid >> 6;
    const int cl = lane & 15, hi = lane >> 4;
    bf16x8 afrag[4][8];
    #pragma unroll
    for (int m = 0; m < 4; ++m)
        #pragma unroll
        for (int k8 = 0; k8 < 8; ++k8)
            afrag[m][k8] = *(const bf16x8*)&AL[(m * 16 + cl) * 260 + k8 * 32 + hi * 8];
    __syncthreads();   // afrag fully read before AL is reused as C-stage

    const size_t rowbase = (size_t)blockIdx.x * 64;
    const int srow = tid >> 2, sq = tid & 3;      // store roles

    for (int ch = 0; ch < 9; ++ch) {
        f32x4 acc[4][3];
        #pragma unroll
        for (int m = 0; m < 4; ++m)
            #pragma unroll
            for (int j = 0; j < 3; ++j)
                acc[m][j] = (f32x4){0.f, 0.f, 0.f, 0.f};
        #pragma unroll
        for (int ks = 0; ks < 8; ++ks) {
            bf16x8 bfrag[3];
            #pragma unroll
            for (int j = 0; j < 3; ++j) {
                int col = ch * 192 + nq * 48 + j * 16 + cl;
                bfrag[j] = *(const bf16x8*)&w2t[(size_t)col * 256 + ks * 32 + hi * 8];
            }
            #pragma unroll
            for (int m = 0; m < 4; ++m)
                #pragma unroll
                for (int j = 0; j < 3; ++j)
                    acc[m][j] = __builtin_amdgcn_mfma_f32_16x16x32_bf16(
                        afrag[m][ks], bfrag[j], acc[m][j], 0, 0, 0);
        }
        // scatter C (+bias) into LDS stage: AL[row][lcol], stride 200
        #pragma unroll
        for (int j = 0; j < 3; ++j) {
            int lcol = nq * 48 + j * 16 + cl;
            float bv = b2[ch * 192 + lcol];
            #pragma unroll
            for (int m = 0; m < 4; ++m)
                #pragma unroll
                for (int r = 0; r < 4; ++r)
                    AL[(m * 16 + hi * 4 + r) * 200 + lcol] = f2bf(acc[m][j][r] + bv);
        }
        __syncthreads();
        // cooperative coalesced store: row srow, 6 x b128; lanes 0-3 cover 64B runs
        unsigned short* dst = lw + (rowbase + srow) * NOUT + ch * 192;
        #pragma unroll
        for (int s = 0; s < 6; ++s) {
            int off = (sq + s * 4) * 8;
            *(u32x4*)(dst + off) = *(const u32x4*)&AL[srow * 200 + off];
        }
        __syncthreads();
    }
}

// ---------------- Kernel 2b: einsum (dynamic conv) + mean-shift -------------------------
// thread = (px, n). lw row streamed as 8-ci groups (27 x b128, all indices static).
__global__ __launch_bounds__(256) void einsum_out(
    const float* __restrict__ feat, const unsigned short* __restrict__ lw,
    float* __restrict__ out)
{
    __shared__ __align__(8) unsigned short FT[64 * 6 * 4 * 6];   // 18432 B, [ci][r6][n4][c6]

    const int tid = threadIdx.x;
    const int bx = blockIdx.x & 31, by = blockIdx.x >> 5;
    const int oy0 = by * 8, ox0 = bx * 8;
    const int h0 = by * 4,  w0 = bx * 4;

    for (int i = tid; i < 64 * 6 * 4 * 6; i += 256) {
        int c = i % 6;
        int t = i / 6;
        int n = t & 3;
        t >>= 2;
        int r  = t % 6;
        int ci = t / 6;
        int gh = h0 - 1 + r, gw = w0 - 1 + c;
        float v = 0.0f;
        if (gh >= 0 && gh < HW && gw >= 0 && gw < HW)
            v = feat[((n * G0n + ci) * HW + gh) * HW + gw];
        FT[i] = f2bf(v);
    }
    __syncthreads();

    const int px = tid >> 2, n = tid & 3;
    const int iy = (px >> 3) >> 1;
    const int ix = (px & 7) >> 1;
    const bool podd = (ix & 1) != 0;
    const int ixa = ix & ~1;

    const u32x4* lwp = (const u32x4*)(lw + ((size_t)blockIdx.x * 64 + px) * NOUT);
    float o0 = 0.f, o1 = 0.f, o2 = 0.f;

    for (int g = 0; g < 8; ++g) {
        // 8 ci per group = 216 shorts = 27 x b128, 16B-aligned (432 B stride)
        u32x4 LA[14], LB[14];
        #pragma unroll
        for (int t = 0; t < 14; ++t) LA[t] = lwp[g * 27 + t];
        #pragma unroll
        for (int t = 0; t < 14; ++t) LB[t] = (t + 13 < 27) ? lwp[g * 27 + 13 + t] : (u32x4){0,0,0,0};

        #pragma unroll
        for (int cl8 = 0; cl8 < 8; ++cl8) {
            int ci = g * 8 + cl8;
            // f-values: fv[di*3+dj] = FT[ci][iy+di][n][ix+dj]
            float fv[9];
            #pragma unroll
            for (int di = 0; di < 3; ++di) {
                int rb = ((ci * 6 + iy + di) * 4 + n) * 6 + ixa;
                unsigned u0 = *(const unsigned*)&FT[rb];
                unsigned u1 = *(const unsigned*)&FT[rb + 2];
                fv[di * 3 + 0] = podd ? bfhi(u0) : bflo(u0);
                fv[di * 3 + 1] = podd ? bflo(u1) : bfhi(u0);
                fv[di * 3 + 2] = podd ? bfhi(u1) : bflo(u1);
            }
            // 27 lw values at static positions
            #pragma unroll
            for (int ktl = 0; ktl < 9; ++ktl) {
                #pragma unroll
                for (int c = 0; c < 3; ++c) {
                    int idx = cl8 * 27 + ktl * 3 + c;          // short index in group, static
                    unsigned d;
                    if (idx < 108) d = LA[idx >> 3][(idx >> 1) & 3];
                    else { int i2 = idx - 104; d = LB[i2 >> 3][(i2 >> 1) & 3]; }
                    float v = (idx & 1) ? bfhi(d) : bflo(d);
                    if (c == 0) o0 = fmaf(fv[ktl], v, o0);
                    else if (c == 1) o1 = fmaf(fv[ktl], v, o1);
                    else o2 = fmaf(fv[ktl], v, o2);
                }
            }
        }
    }

    int oy = oy0 + (px >> 3), ox = ox0 + (px & 7);
    out[((n * 3 + 0) * OHW + oy) * OHW + ox] = o0 + 0.4488f * 255.0f;
    out[((n * 3 + 1) * OHW + oy) * OHW + ox] = o1 + 0.4371f * 255.0f;
    out[((n * 3 + 2) * OHW + oy) * OHW + ox] = o2 + 0.4040f * 255.0f;
}

extern "C" void kernel_launch(void* const* d_in, const int* in_sizes, int n_in,
                              void* d_out, int out_size, void* d_ws, size_t ws_size,
                              hipStream_t stream) {
    (void)in_sizes; (void)n_in; (void)out_size; (void)ws_size;
    const float* x      = (const float*)d_in[0];
    const float* posm   = (const float*)d_in[1];
    const float* conv_w = (const float*)d_in[2];
    const float* conv_b = (const float*)d_in[3];
    const float* w1     = (const float*)d_in[4];
    const float* b1     = (const float*)d_in[5];
    const float* w2     = (const float*)d_in[6];
    const float* b2     = (const float*)d_in[7];
    float* out = (float*)d_out;

    unsigned short* w2t = (unsigned short*)d_ws;                     // 884,736 B
    float* feat = (float*)((char*)d_ws + 884736);                    // 16,777,216 B
    const size_t lw_off = 884736u + 16777216u;                       // 17,661,952
    unsigned short* lwbuf = (unsigned short*)((char*)d_ws + lw_off); // 226,492,416 B

    prep_w2t<<<108, 256, 0, stream>>>(w2, w2t);
    conv5_relu_kernel<<<(NB * G0n * HW * 32) / 256, 256, 0, stream>>>(x, conv_w, conv_b, feat);
    gemm_lw<<<1024, 256, 0, stream>>>(w2t, posm, w1, b1, b2, lwbuf);
    einsum_out<<<1024, 256, 0, stream>>>(feat, lwbuf, out);
}

// Round 9
// 239.470 us; speedup vs baseline: 1.4033x; 1.0041x over previous
//
#include <hip/hip_runtime.h>

#define HW   128
#define OHW  256
#define G0n  64
#define HID  256
#define NOUT 1728
#define NB   4

typedef __attribute__((ext_vector_type(8))) short bf16x8;
typedef __attribute__((ext_vector_type(4))) float f32x4;
typedef __attribute__((ext_vector_type(4))) unsigned int u32x4;
typedef __attribute__((ext_vector_type(2))) unsigned int u32x2;

__device__ __forceinline__ unsigned short f2bf(float f) {
    unsigned int u = __builtin_bit_cast(unsigned int, f);
    u += 0x7fffu + ((u >> 16) & 1u);
    return (unsigned short)(u >> 16);
}
__device__ __forceinline__ float bflo(unsigned int d) {
    return __builtin_bit_cast(float, d << 16);
}
__device__ __forceinline__ float bfhi(unsigned int d) {
    return __builtin_bit_cast(float, d & 0xffff0000u);
}

// Workgroup barrier that waits ONLY on LDS ops (lgkmcnt), not on in-flight
// global stores (vmcnt). HIP __syncthreads drains vmcnt(0) too, which
// serializes the store pipeline at every chunk boundary.
__device__ __forceinline__ void barrier_ldsonly() {
    __builtin_amdgcn_sched_barrier(0);
    asm volatile("s_waitcnt lgkmcnt(0)" ::: "memory");
    __builtin_amdgcn_s_barrier();
    __builtin_amdgcn_sched_barrier(0);
}

// ---------------- Kernel 0: w2 [256][1728] f32 -> w2t [1728][256] bf16 (LDS tiled) ----
__global__ __launch_bounds__(256) void prep_w2t(const float* __restrict__ w2,
                                                unsigned short* __restrict__ w2t) {
    __shared__ float t[64][65];
    int kb = blockIdx.x & 3, cb = blockIdx.x >> 2;
    int lc = threadIdx.x & 63, lr = threadIdx.x >> 6;
    #pragma unroll
    for (int i = 0; i < 16; ++i) {
        int kk = lr + i * 4;
        t[kk][lc] = w2[(kb * 64 + kk) * NOUT + cb * 64 + lc];
    }
    __syncthreads();
    #pragma unroll
    for (int i = 0; i < 16; ++i) {
        int cc = lr + i * 4;
        w2t[(cb * 64 + cc) * 256 + kb * 64 + lc] = f2bf(t[lc][cc]);
    }
}

// ---------------- Kernel 1: 5x5 SAME conv + bias + ReLU, 4 outputs/thread ----------------
__global__ __launch_bounds__(256) void conv5_relu_kernel(
    const float* __restrict__ x, const float* __restrict__ cw,
    const float* __restrict__ cb, float* __restrict__ feat)
{
    int idx = blockIdx.x * 256 + threadIdx.x;
    int w4 = (idx & 31) * 4;
    int h  = (idx >> 5) & 127;
    int g  = (idx >> 12) & 63;
    int n  = idx >> 18;
    float bv = cb[g];
    float a[4] = {bv, bv, bv, bv};
    const float* wp = cw + g * 75;
    #pragma unroll
    for (int ci = 0; ci < 3; ++ci) {
        const float* xr = x + (n * 3 + ci) * (HW * HW);
        #pragma unroll
        for (int ki = 0; ki < 5; ++ki) {
            int hh = h + ki - 2;
            if (hh < 0 || hh >= HW) continue;
            const float* row = xr + hh * HW;
            float f[8];
            if (w4 != 0 && w4 != 124) {
                float2 u0 = *(const float2*)(row + w4 - 2);
                float2 u1 = *(const float2*)(row + w4);
                float2 u2 = *(const float2*)(row + w4 + 2);
                float2 u3 = *(const float2*)(row + w4 + 4);
                f[0] = u0.x; f[1] = u0.y; f[2] = u1.x; f[3] = u1.y;
                f[4] = u2.x; f[5] = u2.y; f[6] = u3.x; f[7] = u3.y;
            } else {
                #pragma unroll
                for (int j = 0; j < 8; ++j) {
                    int ww = w4 - 2 + j;
                    f[j] = (ww >= 0 && ww < HW) ? row[ww] : 0.0f;
                }
            }
            float wt[5];
            #pragma unroll
            for (int kj = 0; kj < 5; ++kj) wt[kj] = wp[ci * 25 + ki * 5 + kj];
            #pragma unroll
            for (int j = 0; j < 4; ++j)
                #pragma unroll
                for (int kj = 0; kj < 5; ++kj)
                    a[j] = fmaf(f[j + kj], wt[kj], a[j]);
        }
    }
    float4 o;
    o.x = fmaxf(a[0], 0.f); o.y = fmaxf(a[1], 0.f);
    o.z = fmaxf(a[2], 0.f); o.w = fmaxf(a[3], 0.f);
    *(float4*)&feat[((n * G0n + g) * HW + h) * HW + w4] = o;
}

// ---------------- Kernel 2a: MFMA GEMM -> lw bf16, LDS repack, lgkm-only barriers -----
// 256 threads (4 waves = 4 N-quarters), M = 64 pixels/block. A in regs, B from L2.
// C chunk staged in LDS, stored as 64B segments; stores never drained mid-kernel.
__global__ __launch_bounds__(256) void gemm_lw(
    const unsigned short* __restrict__ w2t, const float* __restrict__ pos,
    const float* __restrict__ w1, const float* __restrict__ b1,
    const float* __restrict__ b2, unsigned short* __restrict__ lw)
{
    __shared__ __align__(16) unsigned short AL[64 * 260];   // Ahid, then C-stage [64][200]

    const int tid = threadIdx.x;
    const int bx = blockIdx.x & 31, by = blockIdx.x >> 5;
    const int oy0 = by * 8, ox0 = bx * 8;

    // hidden = relu(pos @ w1 + b1) -> AL[px][256]
    {
        int px = tid >> 2, q = tid & 3;
        int rr = (oy0 + (px >> 3)) * OHW + (ox0 + (px & 7));
        float p0 = pos[rr * 3 + 0], p1 = pos[rr * 3 + 1], p2 = pos[rr * 3 + 2];
        #pragma unroll
        for (int j = 0; j < 16; ++j) {
            int k0 = q * 4 + j * 16;
            float4 wa = *(const float4*)&w1[k0];
            float4 wb = *(const float4*)&w1[HID + k0];
            float4 wc = *(const float4*)&w1[2 * HID + k0];
            float4 bb = *(const float4*)&b1[k0];
            unsigned short h0s = f2bf(fmaxf(fmaf(p0, wa.x, fmaf(p1, wb.x, fmaf(p2, wc.x, bb.x))), 0.f));
            unsigned short h1s = f2bf(fmaxf(fmaf(p0, wa.y, fmaf(p1, wb.y, fmaf(p2, wc.y, bb.y))), 0.f));
            unsigned short h2s = f2bf(fmaxf(fmaf(p0, wa.z, fmaf(p1, wb.z, fmaf(p2, wc.z, bb.z))), 0.f));
            unsigned short h3s = f2bf(fmaxf(fmaf(p0, wa.w, fmaf(p1, wb.w, fmaf(p2, wc.w, bb.w))), 0.f));
            u32x2 pk;
            pk.x = (unsigned)h0s | ((unsigned)h1s << 16);
            pk.y = (unsigned)h2s | ((unsigned)h3s << 16);
            *(u32x2*)&AL[px * 260 + k0] = pk;
        }
    }
    __syncthreads();

    const int lane = tid & 63, nq = tid >> 6;
    const int cl = lane & 15, hi = lane >> 4;
    bf16x8 afrag[4][8];
    #pragma unroll
    for (int m = 0; m < 4; ++m)
        #pragma unroll
        for (int k8 = 0; k8 < 8; ++k8)
            afrag[m][k8] = *(const bf16x8*)&AL[(m * 16 + cl) * 260 + k8 * 32 + hi * 8];
    __syncthreads();   // afrag fully read before AL is reused as C-stage

    const size_t rowbase = (size_t)blockIdx.x * 64;
    const int srow = tid >> 2, sq = tid & 3;      // store roles

    for (int ch = 0; ch < 9; ++ch) {
        f32x4 acc[4][3];
        #pragma unroll
        for (int m = 0; m < 4; ++m)
            #pragma unroll
            for (int j = 0; j < 3; ++j)
                acc[m][j] = (f32x4){0.f, 0.f, 0.f, 0.f};
        #pragma unroll
        for (int ks = 0; ks < 8; ++ks) {
            bf16x8 bfrag[3];
            #pragma unroll
            for (int j = 0; j < 3; ++j) {
                int col = ch * 192 + nq * 48 + j * 16 + cl;
                bfrag[j] = *(const bf16x8*)&w2t[(size_t)col * 256 + ks * 32 + hi * 8];
            }
            #pragma unroll
            for (int m = 0; m < 4; ++m)
                #pragma unroll
                for (int j = 0; j < 3; ++j)
                    acc[m][j] = __builtin_amdgcn_mfma_f32_16x16x32_bf16(
                        afrag[m][ks], bfrag[j], acc[m][j], 0, 0, 0);
        }
        // barrier A: prev store-phase LDS reads done (lgkm only; stores stay in flight)
        barrier_ldsonly();
        // scatter C (+bias) into LDS stage: AL[row][lcol], stride 200
        #pragma unroll
        for (int j = 0; j < 3; ++j) {
            int lcol = nq * 48 + j * 16 + cl;
            float bv = b2[ch * 192 + lcol];
            #pragma unroll
            for (int m = 0; m < 4; ++m)
                #pragma unroll
                for (int r = 0; r < 4; ++r)
                    AL[(m * 16 + hi * 4 + r) * 200 + lcol] = f2bf(acc[m][j][r] + bv);
        }
        // barrier B: scatter writes visible to store phase (lgkm only)
        barrier_ldsonly();
        // cooperative coalesced store: row srow, 6 x b128; lanes 0-3 cover 64B runs
        unsigned short* dst = lw + (rowbase + srow) * NOUT + ch * 192;
        #pragma unroll
        for (int s = 0; s < 6; ++s) {
            int off = (sq + s * 4) * 8;
            *(u32x4*)(dst + off) = *(const u32x4*)&AL[srow * 200 + off];
        }
    }
}

// ---------------- Kernel 2b: einsum (dynamic conv) + mean-shift -------------------------
// thread = (px, n). lw row streamed as 8-ci groups (27 x b128, all indices static).
__global__ __launch_bounds__(256) void einsum_out(
    const float* __restrict__ feat, const unsigned short* __restrict__ lw,
    float* __restrict__ out)
{
    __shared__ __align__(8) unsigned short FT[64 * 6 * 4 * 6];   // 18432 B, [ci][r6][n4][c6]

    const int tid = threadIdx.x;
    const int bx = blockIdx.x & 31, by = blockIdx.x >> 5;
    const int oy0 = by * 8, ox0 = bx * 8;
    const int h0 = by * 4,  w0 = bx * 4;

    for (int i = tid; i < 64 * 6 * 4 * 6; i += 256) {
        int c = i % 6;
        int t = i / 6;
        int n = t & 3;
        t >>= 2;
        int r  = t % 6;
        int ci = t / 6;
        int gh = h0 - 1 + r, gw = w0 - 1 + c;
        float v = 0.0f;
        if (gh >= 0 && gh < HW && gw >= 0 && gw < HW)
            v = feat[((n * G0n + ci) * HW + gh) * HW + gw];
        FT[i] = f2bf(v);
    }
    __syncthreads();

    const int px = tid >> 2, n = tid & 3;
    const int iy = (px >> 3) >> 1;
    const int ix = (px & 7) >> 1;
    const bool podd = (ix & 1) != 0;
    const int ixa = ix & ~1;

    const u32x4* lwp = (const u32x4*)(lw + ((size_t)blockIdx.x * 64 + px) * NOUT);
    float o0 = 0.f, o1 = 0.f, o2 = 0.f;

    for (int g = 0; g < 8; ++g) {
        // 8 ci per group = 216 shorts = 27 x b128, 16B-aligned (432 B stride)
        u32x4 LA[14], LB[14];
        #pragma unroll
        for (int t = 0; t < 14; ++t) LA[t] = lwp[g * 27 + t];
        #pragma unroll
        for (int t = 0; t < 14; ++t) LB[t] = (t + 13 < 27) ? lwp[g * 27 + 13 + t] : (u32x4){0,0,0,0};

        #pragma unroll
        for (int cl8 = 0; cl8 < 8; ++cl8) {
            int ci = g * 8 + cl8;
            // f-values: fv[di*3+dj] = FT[ci][iy+di][n][ix+dj]
            float fv[9];
            #pragma unroll
            for (int di = 0; di < 3; ++di) {
                int rb = ((ci * 6 + iy + di) * 4 + n) * 6 + ixa;
                unsigned u0 = *(const unsigned*)&FT[rb];
                unsigned u1 = *(const unsigned*)&FT[rb + 2];
                fv[di * 3 + 0] = podd ? bfhi(u0) : bflo(u0);
                fv[di * 3 + 1] = podd ? bflo(u1) : bfhi(u0);
                fv[di * 3 + 2] = podd ? bfhi(u1) : bflo(u1);
            }
            // 27 lw values at static positions
            #pragma unroll
            for (int ktl = 0; ktl < 9; ++ktl) {
                #pragma unroll
                for (int c = 0; c < 3; ++c) {
                    int idx = cl8 * 27 + ktl * 3 + c;          // short index in group, static
                    unsigned d;
                    if (idx < 108) d = LA[idx >> 3][(idx >> 1) & 3];
                    else { int i2 = idx - 104; d = LB[i2 >> 3][(i2 >> 1) & 3]; }
                    float v = (idx & 1) ? bfhi(d) : bflo(d);
                    if (c == 0) o0 = fmaf(fv[ktl], v, o0);
                    else if (c == 1) o1 = fmaf(fv[ktl], v, o1);
                    else o2 = fmaf(fv[ktl], v, o2);
                }
            }
        }
    }

    int oy = oy0 + (px >> 3), ox = ox0 + (px & 7);
    out[((n * 3 + 0) * OHW + oy) * OHW + ox] = o0 + 0.4488f * 255.0f;
    out[((n * 3 + 1) * OHW + oy) * OHW + ox] = o1 + 0.4371f * 255.0f;
    out[((n * 3 + 2) * OHW + oy) * OHW + ox] = o2 + 0.4040f * 255.0f;
}

extern "C" void kernel_launch(void* const* d_in, const int* in_sizes, int n_in,
                              void* d_out, int out_size, void* d_ws, size_t ws_size,
                              hipStream_t stream) {
    (void)in_sizes; (void)n_in; (void)out_size; (void)ws_size;
    const float* x      = (const float*)d_in[0];
    const float* posm   = (const float*)d_in[1];
    const float* conv_w = (const float*)d_in[2];
    const float* conv_b = (const float*)d_in[3];
    const float* w1     = (const float*)d_in[4];
    const float* b1     = (const float*)d_in[5];
    const float* w2     = (const float*)d_in[6];
    const float* b2     = (const float*)d_in[7];
    float* out = (float*)d_out;

    unsigned short* w2t = (unsigned short*)d_ws;                     // 884,736 B
    float* feat = (float*)((char*)d_ws + 884736);                    // 16,777,216 B
    const size_t lw_off = 884736u + 16777216u;                       // 17,661,952
    unsigned short* lwbuf = (unsigned short*)((char*)d_ws + lw_off); // 226,492,416 B

    prep_w2t<<<108, 256, 0, stream>>>(w2, w2t);
    conv5_relu_kernel<<<(NB * G0n * HW * 32) / 256, 256, 0, stream>>>(x, conv_w, conv_b, feat);
    gemm_lw<<<1024, 256, 0, stream>>>(w2t, posm, w1, b1, b2, lwbuf);
    einsum_out<<<1024, 256, 0, stream>>>(feat, lwbuf, out);
}